// Round 9
// baseline (1087.392 us; speedup 1.0000x reference)
//
// HNHN layer on MI355X (gfx950). Round 11: ATTRIBUTION PROBE.
// Identical to R10 (passed, 956.2us) except MM1 and MM2 are each launched
// TWICE (idempotent pure-function writes -> bit-identical outputs).
// Delta vs 956 = T_MM1 + T_MM2, finally measured directly after 7 null
// MM experiments built on an unverified attribution.
// Pre-committed readout: >=350 -> MMs dominate, attack occupancy (4 blk/CU);
// 120-250 -> MMs near floor, pivot; <=100 -> harness-fixed cost dominates.
#include <hip/hip_runtime.h>
#include <stdint.h>

#define NN 16384
#define NE 8192
#define CH 256
#define MM1_SPLIT 8
#define MM2_SPLIT 4

typedef __attribute__((ext_vector_type(8))) short bf16x8;
typedef __attribute__((ext_vector_type(4))) float f32x4;

__device__ __forceinline__ unsigned short f2bf(float f) {  // RNE fp32->bf16
  unsigned u = __float_as_uint(f);
  u += 0x7FFFu + ((u >> 16) & 1u);
  return (unsigned short)(u >> 16);
}
__device__ __forceinline__ void async_copy16(const void* gptr, void* lptr) {
  __builtin_amdgcn_global_load_lds((const __attribute__((address_space(1))) unsigned int*)gptr,
                                   (__attribute__((address_space(3))) unsigned int*)lptr,
                                   16, 0, 0);
}
// expand 8 A-bits -> 8 bf16 {0,1} packed in uint4 (2 bf16 per u32); bf16[j]=bit j
__device__ __forceinline__ uint4 expand8(unsigned byte) {
  uint4 aw;
#pragma unroll
  for (int j = 0; j < 4; ++j) {
    unsigned lo = (byte >> (2 * j)) & 1u;
    unsigned hi = (byte >> (2 * j + 1)) & 1u;
    ((unsigned*)&aw)[j] = lo * 0x3F80u + hi * 0x3F800000u;
  }
  return aw;
}

// LSB-first 32x32 bit transpose: result x'[k] bit j == input x[j] bit k.
__device__ __forceinline__ void transpose32(unsigned* x) {
  const unsigned masks[5] = {0x0000FFFFu, 0x00FF00FFu, 0x0F0F0F0Fu, 0x33333333u, 0x55555555u};
#pragma unroll
  for (int jj = 0; jj < 5; ++jj) {
    const int j = 16 >> jj;
    const unsigned m = masks[jj];
#pragma unroll
    for (int k = 0; k < 32; ++k) {
      if ((k & j) == 0) {
        unsigned t = ((x[k] >> j) ^ x[k + j]) & m;
        x[k] ^= (t << j);
        x[k + j] ^= t;
      }
    }
  }
}

// ---------------- K0: weight transpose to bf16 ----------------
__global__ void k0_transpose_w(const float* __restrict__ W0, const float* __restrict__ W1,
                               unsigned short* __restrict__ W0T, unsigned short* __restrict__ W1T) {
  const float* W = blockIdx.y ? W1 : W0;
  unsigned short* WT = blockIdx.y ? W1T : W0T;
  int n = blockIdx.x;
  int k = threadIdx.x;
  WT[n * CH + k] = f2bf(W[k * CH + n]);
}

// ---------------- K1: pack B1 row to bits + node_card ----------------
__global__ void k1_pack_card(const float* __restrict__ B1, unsigned* __restrict__ pk1,
                             float* __restrict__ node_card) {
  int n = blockIdx.x;
  int t = threadIdx.x;
  const float4* p = (const float4*)(B1 + (size_t)n * NE + t * 32);
  unsigned w = 0;
#pragma unroll
  for (int jj = 0; jj < 8; ++jj) {
    float4 v = p[jj];
    w |= ((__float_as_uint(v.x) >> 23) & 1u) << (4 * jj);
    w |= ((__float_as_uint(v.y) >> 23) & 1u) << (4 * jj + 1);
    w |= ((__float_as_uint(v.z) >> 23) & 1u) << (4 * jj + 2);
    w |= ((__float_as_uint(v.w) >> 23) & 1u) << (4 * jj + 3);
  }
  pk1[(size_t)n * 256 + t] = w;
  int s = __popc(w);
  __shared__ int red[4];
#pragma unroll
  for (int off = 32; off; off >>= 1) s += __shfl_down(s, off, 64);
  if ((t & 63) == 0) red[t >> 6] = s;
  __syncthreads();
  if (t == 0) {
    float tot = (float)(red[0] + red[1] + red[2] + red[3]);
    node_card[n] = rsqrtf(tot);
  }
}

// ---------------- K1b: bit transpose pk1 -> pk1T ----------------
__global__ __launch_bounds__(256) void k1b_bitT(const unsigned* __restrict__ pk1,
                                                unsigned* __restrict__ pk1T) {
  int bw = blockIdx.x & 127;   // e-word pair: words 2bw, 2bw+1 (e-range 64)
  int half = blockIdx.x >> 7;  // which half of the 512 n-tiles
  int t = threadIdx.x;
  int nt = half * 256 + t;     // n-word tile 0..511
  unsigned x0[32], x1[32];
#pragma unroll
  for (int r = 0; r < 32; ++r) {
    uint2 v = *(const uint2*)&pk1[(size_t)(nt * 32 + r) * 256 + 2 * bw];
    x0[r] = v.x;
    x1[r] = v.y;
  }
  transpose32(x0);
  transpose32(x1);
  int e0 = bw * 64;
#pragma unroll
  for (int c = 0; c < 32; ++c) {
    pk1T[(size_t)(e0 + c) * 512 + nt] = x0[c];
    pk1T[(size_t)(e0 + 32 + c) * 512 + nt] = x1[c];
  }
}

// ---------------- KE: edge_card + d1 from pk1T (fp32 weighted popcount) ----
__global__ __launch_bounds__(256) void ke_edge(const unsigned* __restrict__ pk1T,
                                               const float* __restrict__ node_card,
                                               float* __restrict__ edge_card,
                                               float* __restrict__ d1) {
  const int t = threadIdx.x;
  const int e0 = blockIdx.x * 4;
  unsigned w[4][2];
#pragma unroll
  for (int r = 0; r < 4; ++r) {
    w[r][0] = pk1T[(size_t)(e0 + r) * 512 + t];
    w[r][1] = pk1T[(size_t)(e0 + r) * 512 + 256 + t];
  }
  float wsum[4] = {0.f, 0.f, 0.f, 0.f};
  int cnt[4];
#pragma unroll
  for (int r = 0; r < 4; ++r) cnt[r] = __popc(w[r][0]) + __popc(w[r][1]);
  const float4* nc0 = (const float4*)(node_card + (size_t)t * 32);
  const float4* nc1 = (const float4*)(node_card + ((size_t)t + 256) * 32);
#pragma unroll
  for (int h = 0; h < 2; ++h) {
    const float4* ncp = h ? nc1 : nc0;
#pragma unroll
    for (int q = 0; q < 8; ++q) {
      float4 v = ncp[q];
#pragma unroll
      for (int r = 0; r < 4; ++r) {
        unsigned ww = w[r][h];
        wsum[r] += ((ww >> (4 * q)) & 1u) ? v.x : 0.f;
        wsum[r] += ((ww >> (4 * q + 1)) & 1u) ? v.y : 0.f;
        wsum[r] += ((ww >> (4 * q + 2)) & 1u) ? v.z : 0.f;
        wsum[r] += ((ww >> (4 * q + 3)) & 1u) ? v.w : 0.f;
      }
    }
  }
#pragma unroll
  for (int off = 32; off; off >>= 1)
#pragma unroll
    for (int r = 0; r < 4; ++r) {
      wsum[r] += __shfl_down(wsum[r], off, 64);
      cnt[r] += __shfl_down(cnt[r], off, 64);
    }
  __shared__ float redW[4][4];
  __shared__ int redC[4][4];
  int wave = t >> 6, lane = t & 63;
  if (lane == 0)
#pragma unroll
    for (int r = 0; r < 4; ++r) {
      redW[wave][r] = wsum[r];
      redC[wave][r] = cnt[r];
    }
  __syncthreads();
  if (t < 4) {
    float s = redW[0][t] + redW[1][t] + redW[2][t] + redW[3][t];
    float c = (float)(redC[0][t] + redC[1][t] + redC[2][t] + redC[3][t]);
    d1[e0 + t] = s;
    edge_card[e0 + t] = 1.0f / (c * sqrtf(c));  // c^-1.5
  }
}

// ---------------- KD0: d0 from pk1 (weighted popcount by edge_card) --------
__global__ __launch_bounds__(256) void kd0_node(const unsigned* __restrict__ pk1,
                                                const float* __restrict__ edge_card,
                                                float* __restrict__ d0) {
  const int t = threadIdx.x;
  const int n0 = blockIdx.x * 4;
  unsigned w[4];
#pragma unroll
  for (int r = 0; r < 4; ++r) w[r] = pk1[(size_t)(n0 + r) * 256 + t];
  float wsum[4] = {0.f, 0.f, 0.f, 0.f};
  const float4* ecp = (const float4*)(edge_card + (size_t)t * 32);
#pragma unroll
  for (int q = 0; q < 8; ++q) {
    float4 v = ecp[q];
#pragma unroll
    for (int r = 0; r < 4; ++r) {
      unsigned ww = w[r];
      wsum[r] += ((ww >> (4 * q)) & 1u) ? v.x : 0.f;
      wsum[r] += ((ww >> (4 * q + 1)) & 1u) ? v.y : 0.f;
      wsum[r] += ((ww >> (4 * q + 2)) & 1u) ? v.z : 0.f;
      wsum[r] += ((ww >> (4 * q + 3)) & 1u) ? v.w : 0.f;
    }
  }
#pragma unroll
  for (int off = 32; off; off >>= 1)
#pragma unroll
    for (int r = 0; r < 4; ++r) wsum[r] += __shfl_down(wsum[r], off, 64);
  __shared__ float redW[4][4];
  int wave = t >> 6, lane = t & 63;
  if (lane == 0)
#pragma unroll
    for (int r = 0; r < 4; ++r) redW[wave][r] = wsum[r];
  __syncthreads();
  if (t < 4) d0[n0 + t] = redW[0][t] + redW[1][t] + redW[2][t] + redW[3][t];
}

// ---------------- K2: y0 GEMM (BM=32, swizzled LDS) ----------
__global__ __launch_bounds__(256) void k2_y0(const float* __restrict__ X0,
                                             const unsigned short* __restrict__ W0T,
                                             const float* __restrict__ node_card,
                                             unsigned short* __restrict__ y0sT) {
  __shared__ __align__(16) unsigned short a_lds[32 * 32];
  __shared__ __align__(16) unsigned short b_lds[256 * 32];
  const int tid = threadIdx.x;
  const int wave = tid >> 6, lane = tid & 63;
  const int quad = lane >> 4, l15 = lane & 15;
  const int m0 = blockIdx.x * 32;
  const int ar = tid >> 3, ac = (tid & 7) * 4;
  const int acs = (((ac >> 3) ^ ((ar >> 1) & 3)) * 8) + (ac & 4);  // swizzled A col (shorts)
  const int bswz = ((lane & 3) ^ ((lane >> 3) & 3)) * 8;           // staging source col swizzle
  const int rg = (l15 >> 1) & 3;                                   // read group swizzle

  f32x4 acc[2][4];
  const f32x4 fz = {0.f, 0.f, 0.f, 0.f};
#pragma unroll
  for (int i = 0; i < 2; ++i)
#pragma unroll
    for (int j = 0; j < 4; ++j) acc[i][j] = fz;

  for (int k0 = 0; k0 < CH; k0 += 32) {
    __syncthreads();
    {
      float4 v = *(const float4*)(X0 + (size_t)(m0 + ar) * CH + k0 + ac);
      uint2 w;
      w.x = ((unsigned)f2bf(v.x)) | ((unsigned)f2bf(v.y) << 16);
      w.y = ((unsigned)f2bf(v.z)) | ((unsigned)f2bf(v.w) << 16);
      *(uint2*)&a_lds[ar * 32 + acs] = w;
    }
#pragma unroll
    for (int i = 0; i < 4; ++i) {
      int rowbase = wave * 64 + i * 16;
      const unsigned short* g = W0T + (size_t)(rowbase + (lane >> 2)) * CH + k0 + bswz;
      async_copy16(g, &b_lds[rowbase * 32]);
    }
    __syncthreads();
    bf16x8 af[2];
#pragma unroll
    for (int i = 0; i < 2; ++i)
      af[i] = *(const bf16x8*)&a_lds[(i * 16 + l15) * 32 + (quad ^ rg) * 8];
#pragma unroll
    for (int j = 0; j < 4; ++j) {
      bf16x8 bfr = *(const bf16x8*)&b_lds[(wave * 64 + j * 16 + l15) * 32 + (quad ^ rg) * 8];
#pragma unroll
      for (int i = 0; i < 2; ++i)
        acc[i][j] = __builtin_amdgcn_mfma_f32_16x16x32_bf16(af[i], bfr, acc[i][j], 0, 0, 0);
    }
  }
#pragma unroll
  for (int i = 0; i < 2; ++i) {
    int row4 = m0 + i * 16 + quad * 4;
    float4 nc = *(const float4*)(node_card + row4);
#pragma unroll
    for (int j = 0; j < 4; ++j) {
      int col = wave * 64 + j * 16 + l15;
      f32x4 v = acc[i][j];
      ushort4 o;
      o.x = f2bf(v[0] * nc.x);
      o.y = f2bf(v[1] * nc.y);
      o.z = f2bf(v[2] * nc.z);
      o.w = f2bf(v[3] * nc.w);
      *(ushort4*)&y0sT[(size_t)col * NN + row4] = o;
    }
  }
}

// ---------------- MM1: B1^T @ y0s (BM=128, split=8, XCD-pinned, counted-vmcnt)
__global__ __launch_bounds__(512, 4) void mm1_kernel(const unsigned char* __restrict__ pk1T,
                                                     const unsigned short* __restrict__ y0sT,
                                                     float* __restrict__ mm1p) {
  __shared__ __align__(16) unsigned short a_lds[2][128 * 40];
  __shared__ __align__(16) unsigned short b_lds[2][256 * 32];
  const int tid = threadIdx.x;
  const int wave = tid >> 6, lane = tid & 63;
  const int quad = lane >> 4, l15 = lane & 15;
  const int wm = wave >> 2, wn = wave & 3;
  const int bid = blockIdx.x;
  const int sp = bid & 7;            // XCD-pinned K-split
  const int m0 = (bid >> 3) * 128;   // e-range
  const int KS = NN / MM1_SPLIT;     // 2048
  const int NT = KS / 32;            // 64
  const int kbase = sp * KS;

  const int am = tid >> 2;                 // e-row within tile (0..127)
  const int akg = tid & 3;                 // logical k-group (8 bf16 = 1 byte)
  const int ajbs = akg ^ ((am >> 4) & 3);  // swizzled physical group
  const int aoff = am * 40 + ajbs * 8;
  const int brow = lane >> 2;
  const int bswz = ((lane & 3) ^ ((lane >> 3) & 3)) * 8;  // staging source col swizzle
  const int rg = (l15 >> 1) & 3;                          // B read group swizzle

  f32x4 acc[4][4];
  const f32x4 fz = {0.f, 0.f, 0.f, 0.f};
#pragma unroll
  for (int i = 0; i < 4; ++i)
#pragma unroll
    for (int j = 0; j < 4; ++j) acc[i][j] = fz;

  const unsigned char* agp = pk1T + (size_t)(m0 + am) * (NN / 8) + (kbase >> 3) + akg;
  unsigned ab_cur = agp[0];  // byte for tile 0
  unsigned ab_nxt = agp[4];  // byte for tile 1
  const unsigned char* agq = agp + 8;

  // prologue: stage tile 0 into buffer 0; full drain once
#pragma unroll
  for (int i = 0; i < 2; ++i) {
    int rowbase = wave * 32 + i * 16;
    const unsigned short* g = y0sT + (size_t)(rowbase + brow) * NN + kbase + bswz;
    async_copy16(g, &b_lds[0][rowbase * 32]);
  }
  *(uint4*)&a_lds[0][aoff] = expand8(ab_cur);
  __syncthreads();

  for (int t = 0; t < NT; ++t) {
    const int cur = t & 1;
    unsigned ab_new = 0;
    if (t + 1 < NT) {  // stage tile t+1 into buffer cur^1 (uniform branch)
      const int k0n = kbase + (t + 1) * 32;
#pragma unroll
      for (int i = 0; i < 2; ++i) {
        int rowbase = wave * 32 + i * 16;
        const unsigned short* g = y0sT + (size_t)(rowbase + brow) * NN + k0n + bswz;
        async_copy16(g, &b_lds[cur ^ 1][rowbase * 32]);
      }
      *(uint4*)&a_lds[cur ^ 1][aoff] = expand8(ab_nxt);
      if (t + 2 < NT) {
        ab_new = *agq;
        agq += 4;
        // outstanding: [t c1,c2 | t+1 c1,c2, byte] -> allow 3 newest in flight
        asm volatile("s_waitcnt vmcnt(3) lgkmcnt(0)" ::: "memory");
      } else {
        // outstanding: [t c1,c2 | t+1 c1,c2] -> allow 2 newest in flight
        asm volatile("s_waitcnt vmcnt(2) lgkmcnt(0)" ::: "memory");
      }
    } else {
      asm volatile("s_waitcnt vmcnt(0) lgkmcnt(0)" ::: "memory");
    }
    __builtin_amdgcn_s_barrier();       // tile t staged & visible; t+1 stays in flight
    __builtin_amdgcn_sched_barrier(0);  // no ds_read hoisted above the barrier
    bf16x8 af[4];
#pragma unroll
    for (int i = 0; i < 4; ++i) {
      int m = wm * 64 + i * 16 + l15;
      int jbs = quad ^ ((m >> 4) & 3);
      af[i] = *(const bf16x8*)&a_lds[cur][m * 40 + jbs * 8];
    }
    __builtin_amdgcn_s_setprio(1);
#pragma unroll
    for (int j = 0; j < 4; ++j) {
      bf16x8 bfr = *(const bf16x8*)&b_lds[cur][(wn * 64 + j * 16 + l15) * 32 + (quad ^ rg) * 8];
#pragma unroll
      for (int i = 0; i < 4; ++i)
        acc[i][j] = __builtin_amdgcn_mfma_f32_16x16x32_bf16(af[i], bfr, acc[i][j], 0, 0, 0);
    }
    __builtin_amdgcn_s_setprio(0);
    __builtin_amdgcn_sched_barrier(0);  // keep reads above barrier2
    __builtin_amdgcn_s_barrier();       // all reads of buf[cur] done; reusable next iter
    ab_cur = ab_nxt;
    ab_nxt = ab_new;
  }
  float* outp = mm1p + (size_t)sp * NE * CH;
#pragma unroll
  for (int i = 0; i < 4; ++i) {
    int row4 = m0 + wm * 64 + i * 16 + quad * 4;
#pragma unroll
    for (int j = 0; j < 4; ++j) {
      int col = wn * 64 + j * 16 + l15;
#pragma unroll
      for (int r = 0; r < 4; ++r) outp[(size_t)(row4 + r) * CH + col] = acc[i][j][r];
    }
  }
}

// ---------------- K3: edge finalize (float4, reduce 8 partials, /d1) -------
__global__ __launch_bounds__(256) void k3_edge_final(const float* __restrict__ mm1p,
                                                     const float* __restrict__ d1,
                                                     const float* __restrict__ b01,
                                                     float* __restrict__ out1,
                                                     unsigned short* __restrict__ x1bf) {
  const int t = threadIdx.x;
  const int e = blockIdx.x * 4 + (t >> 6);
  const int c4 = (t & 63) * 4;
  float px = 0.f, py = 0.f, pz = 0.f, pw = 0.f;
#pragma unroll
  for (int sp = 0; sp < MM1_SPLIT; ++sp) {
    float4 v = *(const float4*)&mm1p[(size_t)sp * NE * CH + (size_t)e * CH + c4];
    px += v.x; py += v.y; pz += v.z; pw += v.w;
  }
  const float rd = 1.0f / d1[e];
  const float4 b = *(const float4*)&b01[c4];
  float4 x1;
  x1.x = px * rd + b.x;
  x1.y = py * rd + b.y;
  x1.z = pz * rd + b.z;
  x1.w = pw * rd + b.w;
  float4 o;
  o.x = fmaxf(x1.x, 0.f); o.y = fmaxf(x1.y, 0.f);
  o.z = fmaxf(x1.z, 0.f); o.w = fmaxf(x1.w, 0.f);
  *(float4*)&out1[(size_t)e * CH + c4] = o;
  ushort4 xb;
  xb.x = f2bf(x1.x); xb.y = f2bf(x1.y); xb.z = f2bf(x1.z); xb.w = f2bf(x1.w);
  *(ushort4*)&x1bf[(size_t)e * CH + c4] = xb;
}

// ---------------- K5: y1 GEMM (BM=32, swizzled LDS) ----------
__global__ __launch_bounds__(256) void k5_y1(const unsigned short* __restrict__ x1bf,
                                             const unsigned short* __restrict__ W1T,
                                             const float* __restrict__ edge_card,
                                             unsigned short* __restrict__ y1sT) {
  __shared__ __align__(16) unsigned short a_lds[32 * 32];
  __shared__ __align__(16) unsigned short b_lds[256 * 32];
  const int tid = threadIdx.x;
  const int wave = tid >> 6, lane = tid & 63;
  const int quad = lane >> 4, l15 = lane & 15;
  const int m0 = blockIdx.x * 32;  // e-range
  const int bswz = ((lane & 3) ^ ((lane >> 3) & 3)) * 8;
  const int rg = (l15 >> 1) & 3;

  f32x4 acc[2][4];
  const f32x4 fz = {0.f, 0.f, 0.f, 0.f};
#pragma unroll
  for (int i = 0; i < 2; ++i)
#pragma unroll
    for (int j = 0; j < 4; ++j) acc[i][j] = fz;

  for (int k0 = 0; k0 < CH; k0 += 32) {
    __syncthreads();
    if (wave < 2) {  // A: 16 rows per wave, async copy (guard: a_lds has 32 rows)
      const unsigned short* g = x1bf + (size_t)(m0 + wave * 16 + (lane >> 2)) * CH + k0 + bswz;
      async_copy16(g, &a_lds[(wave * 16) * 32]);
    }
#pragma unroll
    for (int i = 0; i < 4; ++i) {
      int rowbase = wave * 64 + i * 16;
      const unsigned short* g = W1T + (size_t)(rowbase + (lane >> 2)) * CH + k0 + bswz;
      async_copy16(g, &b_lds[rowbase * 32]);
    }
    __syncthreads();
    bf16x8 af[2];
#pragma unroll
    for (int i = 0; i < 2; ++i)
      af[i] = *(const bf16x8*)&a_lds[(i * 16 + l15) * 32 + (quad ^ rg) * 8];
#pragma unroll
    for (int j = 0; j < 4; ++j) {
      bf16x8 bfr = *(const bf16x8*)&b_lds[(wave * 64 + j * 16 + l15) * 32 + (quad ^ rg) * 8];
#pragma unroll
      for (int i = 0; i < 2; ++i)
        acc[i][j] = __builtin_amdgcn_mfma_f32_16x16x32_bf16(af[i], bfr, acc[i][j], 0, 0, 0);
    }
  }
#pragma unroll
  for (int i = 0; i < 2; ++i) {
    int row4 = m0 + i * 16 + quad * 4;
    float4 ec = *(const float4*)(edge_card + row4);
#pragma unroll
    for (int j = 0; j < 4; ++j) {
      int col = wave * 64 + j * 16 + l15;
      f32x4 v = acc[i][j];
      ushort4 o;
      o.x = f2bf(v[0] * ec.x);
      o.y = f2bf(v[1] * ec.y);
      o.z = f2bf(v[2] * ec.z);
      o.w = f2bf(v[3] * ec.w);
      *(ushort4*)&y1sT[(size_t)col * NE + row4] = o;
    }
  }
}

// ---------------- MM2: B1 @ y1s (BM=128, split=4, XCD pair, counted-vmcnt) --
__global__ __launch_bounds__(512, 4) void mm2_kernel(const unsigned char* __restrict__ pk1,
                                                     const unsigned short* __restrict__ y1sT,
                                                     float* __restrict__ mm2p) {
  __shared__ __align__(16) unsigned short a_lds[2][128 * 40];
  __shared__ __align__(16) unsigned short b_lds[2][256 * 32];
  const int tid = threadIdx.x;
  const int wave = tid >> 6, lane = tid & 63;
  const int quad = lane >> 4, l15 = lane & 15;
  const int wm = wave >> 2, wn = wave & 3;
  const int bid = blockIdx.x;
  const int sp = (bid >> 1) & 3;                         // XCD pair {2sp,2sp+1}
  const int m0 = (((bid >> 3) << 1) | (bid & 1)) * 128;  // node-range
  const int KS = NE / MM2_SPLIT;                         // 2048
  const int NT = KS / 32;                                // 64
  const int kbase = sp * KS;

  const int am = tid >> 2;
  const int akg = tid & 3;
  const int ajbs = akg ^ ((am >> 4) & 3);
  const int aoff = am * 40 + ajbs * 8;
  const int brow = lane >> 2;
  const int bswz = ((lane & 3) ^ ((lane >> 3) & 3)) * 8;
  const int rg = (l15 >> 1) & 3;

  f32x4 acc[4][4];
  const f32x4 fz = {0.f, 0.f, 0.f, 0.f};
#pragma unroll
  for (int i = 0; i < 4; ++i)
#pragma unroll
    for (int j = 0; j < 4; ++j) acc[i][j] = fz;

  const unsigned char* agp = pk1 + (size_t)(m0 + am) * (NE / 8) + (kbase >> 3) + akg;
  unsigned ab_cur = agp[0];
  unsigned ab_nxt = agp[4];
  const unsigned char* agq = agp + 8;

  // prologue: stage tile 0 into buffer 0; full drain once
#pragma unroll
  for (int i = 0; i < 2; ++i) {
    int rowbase = wave * 32 + i * 16;
    const unsigned short* g = y1sT + (size_t)(rowbase + brow) * NE + kbase + bswz;
    async_copy16(g, &b_lds[0][rowbase * 32]);
  }
  *(uint4*)&a_lds[0][aoff] = expand8(ab_cur);
  __syncthreads();

  for (int t = 0; t < NT; ++t) {
    const int cur = t & 1;
    unsigned ab_new = 0;
    if (t + 1 < NT) {
      const int k0n = kbase + (t + 1) * 32;
#pragma unroll
      for (int i = 0; i < 2; ++i) {
        int rowbase = wave * 32 + i * 16;
        const unsigned short* g = y1sT + (size_t)(rowbase + brow) * NE + k0n + bswz;
        async_copy16(g, &b_lds[cur ^ 1][rowbase * 32]);
      }
      *(uint4*)&a_lds[cur ^ 1][aoff] = expand8(ab_nxt);
      if (t + 2 < NT) {
        ab_new = *agq;
        agq += 4;
        asm volatile("s_waitcnt vmcnt(3) lgkmcnt(0)" ::: "memory");
      } else {
        asm volatile("s_waitcnt vmcnt(2) lgkmcnt(0)" ::: "memory");
      }
    } else {
      asm volatile("s_waitcnt vmcnt(0) lgkmcnt(0)" ::: "memory");
    }
    __builtin_amdgcn_s_barrier();
    __builtin_amdgcn_sched_barrier(0);
    bf16x8 af[4];
#pragma unroll
    for (int i = 0; i < 4; ++i) {
      int m = wm * 64 + i * 16 + l15;
      int jbs = quad ^ ((m >> 4) & 3);
      af[i] = *(const bf16x8*)&a_lds[cur][m * 40 + jbs * 8];
    }
    __builtin_amdgcn_s_setprio(1);
#pragma unroll
    for (int j = 0; j < 4; ++j) {
      bf16x8 bfr = *(const bf16x8*)&b_lds[cur][(wn * 64 + j * 16 + l15) * 32 + (quad ^ rg) * 8];
#pragma unroll
      for (int i = 0; i < 4; ++i)
        acc[i][j] = __builtin_amdgcn_mfma_f32_16x16x32_bf16(af[i], bfr, acc[i][j], 0, 0, 0);
    }
    __builtin_amdgcn_s_setprio(0);
    __builtin_amdgcn_sched_barrier(0);
    __builtin_amdgcn_s_barrier();
    ab_cur = ab_nxt;
    ab_nxt = ab_new;
  }
  float* outp = mm2p + (size_t)sp * NN * CH;
#pragma unroll
  for (int i = 0; i < 4; ++i) {
    int row4 = m0 + wm * 64 + i * 16 + quad * 4;
#pragma unroll
    for (int j = 0; j < 4; ++j) {
      int col = wn * 64 + j * 16 + l15;
#pragma unroll
      for (int r = 0; r < 4; ++r) outp[(size_t)(row4 + r) * CH + col] = acc[i][j][r];
    }
  }
}

// ---------------- K6: node finalize (float4, reduce 4 partials, /d0) -------
__global__ __launch_bounds__(256) void k6_node_final(const float* __restrict__ mm2p,
                                                     const float* __restrict__ d0,
                                                     const float* __restrict__ b10,
                                                     float* __restrict__ out0) {
  const int t = threadIdx.x;
  const int n = blockIdx.x * 4 + (t >> 6);
  const int c4 = (t & 63) * 4;
  float sx = 0.f, sy = 0.f, sz = 0.f, sw = 0.f;
#pragma unroll
  for (int sp = 0; sp < MM2_SPLIT; ++sp) {
    float4 v = *(const float4*)&mm2p[(size_t)sp * NN * CH + (size_t)n * CH + c4];
    sx += v.x; sy += v.y; sz += v.z; sw += v.w;
  }
  const float rd = 1.0f / d0[n];
  const float4 b = *(const float4*)&b10[c4];
  float4 o;
  o.x = fmaxf(sx * rd + b.x, 0.f);
  o.y = fmaxf(sy * rd + b.y, 0.f);
  o.z = fmaxf(sz * rd + b.z, 0.f);
  o.w = fmaxf(sw * rd + b.w, 0.f);
  *(float4*)&out0[(size_t)n * CH + c4] = o;
}

extern "C" void kernel_launch(void* const* d_in, const int* in_sizes, int n_in,
                              void* d_out, int out_size, void* d_ws, size_t ws_size,
                              hipStream_t stream) {
  const float* x0 = (const float*)d_in[0];
  const float* B1 = (const float*)d_in[1];
  const float* W0 = (const float*)d_in[2];
  const float* W1 = (const float*)d_in[3];
  const float* b01 = (const float*)d_in[4];
  const float* b10 = (const float*)d_in[5];
  float* out0 = (float*)d_out;
  float* out1 = out0 + (size_t)NN * CH;

  char* ws = (char*)d_ws;
  size_t off = 0;
  auto take = [&](size_t bytes) {
    void* p = ws + off;
    off += (bytes + 255) & ~(size_t)255;
    return p;
  };
  unsigned short* y0sT = (unsigned short*)take((size_t)256 * NN * 2);          // 8.4 MB
  unsigned short* y1sT = (unsigned short*)take((size_t)256 * NE * 2);          // 4.2 MB
  unsigned short* x1bf = (unsigned short*)take((size_t)NE * CH * 2);           // 4.2 MB
  float* mm1p = (float*)take((size_t)MM1_SPLIT * NE * CH * 4);                 // 67.1 MB
  float* mm2p = mm1p;  // alias: mm1p dead after K3; MM2_SPLIT*NN*CH*4 == same size
  float* node_card = (float*)take((size_t)NN * 4);
  float* edge_card = (float*)take((size_t)NE * 4);
  float* d1 = (float*)take((size_t)NE * 4);
  float* d0 = (float*)take((size_t)NN * 4);
  unsigned short* W0T = (unsigned short*)take((size_t)CH * CH * 2);
  unsigned short* W1T = (unsigned short*)take((size_t)CH * CH * 2);
  unsigned* pk1 = (unsigned*)take((size_t)NN * 256 * 4);                       // 16.8 MB packed B1
  unsigned* pk1T = (unsigned*)take((size_t)NE * 512 * 4);                      // 16.8 MB packed B1^T
  (void)ws_size; (void)in_sizes; (void)n_in; (void)out_size;

  k0_transpose_w<<<dim3(256, 2), 256, 0, stream>>>(W0, W1, W0T, W1T);
  k1_pack_card<<<NN, 256, 0, stream>>>(B1, pk1, node_card);
  k1b_bitT<<<256, 256, 0, stream>>>(pk1, pk1T);
  ke_edge<<<NE / 4, 256, 0, stream>>>(pk1T, node_card, edge_card, d1);
  kd0_node<<<NN / 4, 256, 0, stream>>>(pk1, edge_card, d0);
  k2_y0<<<NN / 32, 256, 0, stream>>>(x0, W0T, node_card, y0sT);
  // ATTRIBUTION PROBE: MM1 and MM2 launched twice (idempotent; outputs
  // bit-identical). dur_us delta vs R10's 956.2 == T_MM1 + T_MM2.
  mm1_kernel<<<512, 512, 0, stream>>>((const unsigned char*)pk1T, y0sT, mm1p);
  mm1_kernel<<<512, 512, 0, stream>>>((const unsigned char*)pk1T, y0sT, mm1p);
  k3_edge_final<<<NE / 4, 256, 0, stream>>>(mm1p, d1, b01, out1, x1bf);
  k5_y1<<<NE / 32, 256, 0, stream>>>(x1bf, W1T, edge_card, y1sT);
  mm2_kernel<<<512, 512, 0, stream>>>((const unsigned char*)pk1, y1sT, mm2p);
  mm2_kernel<<<512, 512, 0, stream>>>((const unsigned char*)pk1, y1sT, mm2p);
  k6_node_final<<<NN / 4, 256, 0, stream>>>(mm2p, d0, b10, out0);
}

// Round 10
// 950.311 us; speedup vs baseline: 1.1442x; 1.1442x over previous
//
// HNHN layer on MI355X (gfx950). Round 12 (FINAL): restore best clean kernel
// (R9, 951.8us) after the R11 attribution probe (MM1+MM2 = 131us measured).
// Budget reconciliation: ~670us harness poison-fills inside the timed window
// (fixed), ~131us MMs (~1.8x LDS/MFMA pipe floor; 7 structural levers all
// null), ~155us remaining kernels (K1's mandatory 512MB read ~81us = HBM
// floor). Addressable headroom <=8%, only via low-prior full 8-phase rewrite.
// Pipeline:
//   K0:  W0,W1 -> bf16 transposed (W0T/W1T, [n][k])
//   K1:  pack B1 rows -> pk1[n][256 u32] + node_card = popcnt^-0.5
//   K1b: bit-transpose pk1 -> pk1T[e][512 u32]
//   KE:  edge_card[e] = popcnt^-1.5 ; d1[e] = masked sum node_card
//   KD0: d0[n] = masked sum edge_card
//   K2:  y0 = x0@W0 (MFMA 16x16, BM=32); y0sT[c][n] = bf16(node_card[n]*y0)
//   MM1: mm1p[sp] = B1^T-slice @ y0s (split=8, XCD-pinned, BM=128, dbuf)
//   K3:  x1 = sum(p)/d1+b01; out1=relu; x1bf=bf16(x1)      [float4]
//   K5:  y1 = x1@W1 (MFMA 16x16, BM=32); y1sT[c][e] = bf16(edge_card[e]*y1)
//   MM2: mm2p[sp] = B1-slice @ y1s (split=4, XCD-pair, BM=128, dbuf)
//   K6:  out0 = relu(sum(mm2p)/d0 + b10)                    [float4]
#include <hip/hip_runtime.h>
#include <stdint.h>

#define NN 16384
#define NE 8192
#define CH 256
#define MM1_SPLIT 8
#define MM2_SPLIT 4

typedef __attribute__((ext_vector_type(8))) short bf16x8;
typedef __attribute__((ext_vector_type(4))) float f32x4;

__device__ __forceinline__ unsigned short f2bf(float f) {  // RNE fp32->bf16
  unsigned u = __float_as_uint(f);
  u += 0x7FFFu + ((u >> 16) & 1u);
  return (unsigned short)(u >> 16);
}
__device__ __forceinline__ void async_copy16(const void* gptr, void* lptr) {
  __builtin_amdgcn_global_load_lds((const __attribute__((address_space(1))) unsigned int*)gptr,
                                   (__attribute__((address_space(3))) unsigned int*)lptr,
                                   16, 0, 0);
}
// expand 8 A-bits -> 8 bf16 {0,1} packed in uint4 (2 bf16 per u32); bf16[j]=bit j
__device__ __forceinline__ uint4 expand8(unsigned byte) {
  uint4 aw;
#pragma unroll
  for (int j = 0; j < 4; ++j) {
    unsigned lo = (byte >> (2 * j)) & 1u;
    unsigned hi = (byte >> (2 * j + 1)) & 1u;
    ((unsigned*)&aw)[j] = lo * 0x3F80u + hi * 0x3F800000u;
  }
  return aw;
}

// LSB-first 32x32 bit transpose: result x'[k] bit j == input x[j] bit k.
__device__ __forceinline__ void transpose32(unsigned* x) {
  const unsigned masks[5] = {0x0000FFFFu, 0x00FF00FFu, 0x0F0F0F0Fu, 0x33333333u, 0x55555555u};
#pragma unroll
  for (int jj = 0; jj < 5; ++jj) {
    const int j = 16 >> jj;
    const unsigned m = masks[jj];
#pragma unroll
    for (int k = 0; k < 32; ++k) {
      if ((k & j) == 0) {
        unsigned t = ((x[k] >> j) ^ x[k + j]) & m;
        x[k] ^= (t << j);
        x[k + j] ^= t;
      }
    }
  }
}

// ---------------- K0: weight transpose to bf16 ----------------
__global__ void k0_transpose_w(const float* __restrict__ W0, const float* __restrict__ W1,
                               unsigned short* __restrict__ W0T, unsigned short* __restrict__ W1T) {
  const float* W = blockIdx.y ? W1 : W0;
  unsigned short* WT = blockIdx.y ? W1T : W0T;
  int n = blockIdx.x;
  int k = threadIdx.x;
  WT[n * CH + k] = f2bf(W[k * CH + n]);
}

// ---------------- K1: pack B1 row to bits + node_card ----------------
__global__ void k1_pack_card(const float* __restrict__ B1, unsigned* __restrict__ pk1,
                             float* __restrict__ node_card) {
  int n = blockIdx.x;
  int t = threadIdx.x;
  const float4* p = (const float4*)(B1 + (size_t)n * NE + t * 32);
  unsigned w = 0;
#pragma unroll
  for (int jj = 0; jj < 8; ++jj) {
    float4 v = p[jj];
    w |= ((__float_as_uint(v.x) >> 23) & 1u) << (4 * jj);
    w |= ((__float_as_uint(v.y) >> 23) & 1u) << (4 * jj + 1);
    w |= ((__float_as_uint(v.z) >> 23) & 1u) << (4 * jj + 2);
    w |= ((__float_as_uint(v.w) >> 23) & 1u) << (4 * jj + 3);
  }
  pk1[(size_t)n * 256 + t] = w;
  int s = __popc(w);
  __shared__ int red[4];
#pragma unroll
  for (int off = 32; off; off >>= 1) s += __shfl_down(s, off, 64);
  if ((t & 63) == 0) red[t >> 6] = s;
  __syncthreads();
  if (t == 0) {
    float tot = (float)(red[0] + red[1] + red[2] + red[3]);
    node_card[n] = rsqrtf(tot);
  }
}

// ---------------- K1b: bit transpose pk1 -> pk1T ----------------
__global__ __launch_bounds__(256) void k1b_bitT(const unsigned* __restrict__ pk1,
                                                unsigned* __restrict__ pk1T) {
  int bw = blockIdx.x & 127;   // e-word pair: words 2bw, 2bw+1 (e-range 64)
  int half = blockIdx.x >> 7;  // which half of the 512 n-tiles
  int t = threadIdx.x;
  int nt = half * 256 + t;     // n-word tile 0..511
  unsigned x0[32], x1[32];
#pragma unroll
  for (int r = 0; r < 32; ++r) {
    uint2 v = *(const uint2*)&pk1[(size_t)(nt * 32 + r) * 256 + 2 * bw];
    x0[r] = v.x;
    x1[r] = v.y;
  }
  transpose32(x0);
  transpose32(x1);
  int e0 = bw * 64;
#pragma unroll
  for (int c = 0; c < 32; ++c) {
    pk1T[(size_t)(e0 + c) * 512 + nt] = x0[c];
    pk1T[(size_t)(e0 + 32 + c) * 512 + nt] = x1[c];
  }
}

// ---------------- KE: edge_card + d1 from pk1T (fp32 weighted popcount) ----
__global__ __launch_bounds__(256) void ke_edge(const unsigned* __restrict__ pk1T,
                                               const float* __restrict__ node_card,
                                               float* __restrict__ edge_card,
                                               float* __restrict__ d1) {
  const int t = threadIdx.x;
  const int e0 = blockIdx.x * 4;
  unsigned w[4][2];
#pragma unroll
  for (int r = 0; r < 4; ++r) {
    w[r][0] = pk1T[(size_t)(e0 + r) * 512 + t];
    w[r][1] = pk1T[(size_t)(e0 + r) * 512 + 256 + t];
  }
  float wsum[4] = {0.f, 0.f, 0.f, 0.f};
  int cnt[4];
#pragma unroll
  for (int r = 0; r < 4; ++r) cnt[r] = __popc(w[r][0]) + __popc(w[r][1]);
  const float4* nc0 = (const float4*)(node_card + (size_t)t * 32);
  const float4* nc1 = (const float4*)(node_card + ((size_t)t + 256) * 32);
#pragma unroll
  for (int h = 0; h < 2; ++h) {
    const float4* ncp = h ? nc1 : nc0;
#pragma unroll
    for (int q = 0; q < 8; ++q) {
      float4 v = ncp[q];
#pragma unroll
      for (int r = 0; r < 4; ++r) {
        unsigned ww = w[r][h];
        wsum[r] += ((ww >> (4 * q)) & 1u) ? v.x : 0.f;
        wsum[r] += ((ww >> (4 * q + 1)) & 1u) ? v.y : 0.f;
        wsum[r] += ((ww >> (4 * q + 2)) & 1u) ? v.z : 0.f;
        wsum[r] += ((ww >> (4 * q + 3)) & 1u) ? v.w : 0.f;
      }
    }
  }
#pragma unroll
  for (int off = 32; off; off >>= 1)
#pragma unroll
    for (int r = 0; r < 4; ++r) {
      wsum[r] += __shfl_down(wsum[r], off, 64);
      cnt[r] += __shfl_down(cnt[r], off, 64);
    }
  __shared__ float redW[4][4];
  __shared__ int redC[4][4];
  int wave = t >> 6, lane = t & 63;
  if (lane == 0)
#pragma unroll
    for (int r = 0; r < 4; ++r) {
      redW[wave][r] = wsum[r];
      redC[wave][r] = cnt[r];
    }
  __syncthreads();
  if (t < 4) {
    float s = redW[0][t] + redW[1][t] + redW[2][t] + redW[3][t];
    float c = (float)(redC[0][t] + redC[1][t] + redC[2][t] + redC[3][t]);
    d1[e0 + t] = s;
    edge_card[e0 + t] = 1.0f / (c * sqrtf(c));  // c^-1.5
  }
}

// ---------------- KD0: d0 from pk1 (weighted popcount by edge_card) --------
__global__ __launch_bounds__(256) void kd0_node(const unsigned* __restrict__ pk1,
                                                const float* __restrict__ edge_card,
                                                float* __restrict__ d0) {
  const int t = threadIdx.x;
  const int n0 = blockIdx.x * 4;
  unsigned w[4];
#pragma unroll
  for (int r = 0; r < 4; ++r) w[r] = pk1[(size_t)(n0 + r) * 256 + t];
  float wsum[4] = {0.f, 0.f, 0.f, 0.f};
  const float4* ecp = (const float4*)(edge_card + (size_t)t * 32);
#pragma unroll
  for (int q = 0; q < 8; ++q) {
    float4 v = ecp[q];
#pragma unroll
    for (int r = 0; r < 4; ++r) {
      unsigned ww = w[r];
      wsum[r] += ((ww >> (4 * q)) & 1u) ? v.x : 0.f;
      wsum[r] += ((ww >> (4 * q + 1)) & 1u) ? v.y : 0.f;
      wsum[r] += ((ww >> (4 * q + 2)) & 1u) ? v.z : 0.f;
      wsum[r] += ((ww >> (4 * q + 3)) & 1u) ? v.w : 0.f;
    }
  }
#pragma unroll
  for (int off = 32; off; off >>= 1)
#pragma unroll
    for (int r = 0; r < 4; ++r) wsum[r] += __shfl_down(wsum[r], off, 64);
  __shared__ float redW[4][4];
  int wave = t >> 6, lane = t & 63;
  if (lane == 0)
#pragma unroll
    for (int r = 0; r < 4; ++r) redW[wave][r] = wsum[r];
  __syncthreads();
  if (t < 4) d0[n0 + t] = redW[0][t] + redW[1][t] + redW[2][t] + redW[3][t];
}

// ---------------- K2: y0 GEMM (BM=32, swizzled LDS) ----------
__global__ __launch_bounds__(256) void k2_y0(const float* __restrict__ X0,
                                             const unsigned short* __restrict__ W0T,
                                             const float* __restrict__ node_card,
                                             unsigned short* __restrict__ y0sT) {
  __shared__ __align__(16) unsigned short a_lds[32 * 32];
  __shared__ __align__(16) unsigned short b_lds[256 * 32];
  const int tid = threadIdx.x;
  const int wave = tid >> 6, lane = tid & 63;
  const int quad = lane >> 4, l15 = lane & 15;
  const int m0 = blockIdx.x * 32;
  const int ar = tid >> 3, ac = (tid & 7) * 4;
  const int acs = (((ac >> 3) ^ ((ar >> 1) & 3)) * 8) + (ac & 4);  // swizzled A col (shorts)
  const int bswz = ((lane & 3) ^ ((lane >> 3) & 3)) * 8;           // staging source col swizzle
  const int rg = (l15 >> 1) & 3;                                   // read group swizzle

  f32x4 acc[2][4];
  const f32x4 fz = {0.f, 0.f, 0.f, 0.f};
#pragma unroll
  for (int i = 0; i < 2; ++i)
#pragma unroll
    for (int j = 0; j < 4; ++j) acc[i][j] = fz;

  for (int k0 = 0; k0 < CH; k0 += 32) {
    __syncthreads();
    {
      float4 v = *(const float4*)(X0 + (size_t)(m0 + ar) * CH + k0 + ac);
      uint2 w;
      w.x = ((unsigned)f2bf(v.x)) | ((unsigned)f2bf(v.y) << 16);
      w.y = ((unsigned)f2bf(v.z)) | ((unsigned)f2bf(v.w) << 16);
      *(uint2*)&a_lds[ar * 32 + acs] = w;
    }
#pragma unroll
    for (int i = 0; i < 4; ++i) {
      int rowbase = wave * 64 + i * 16;
      const unsigned short* g = W0T + (size_t)(rowbase + (lane >> 2)) * CH + k0 + bswz;
      async_copy16(g, &b_lds[rowbase * 32]);
    }
    __syncthreads();
    bf16x8 af[2];
#pragma unroll
    for (int i = 0; i < 2; ++i)
      af[i] = *(const bf16x8*)&a_lds[(i * 16 + l15) * 32 + (quad ^ rg) * 8];
#pragma unroll
    for (int j = 0; j < 4; ++j) {
      bf16x8 bfr = *(const bf16x8*)&b_lds[(wave * 64 + j * 16 + l15) * 32 + (quad ^ rg) * 8];
#pragma unroll
      for (int i = 0; i < 2; ++i)
        acc[i][j] = __builtin_amdgcn_mfma_f32_16x16x32_bf16(af[i], bfr, acc[i][j], 0, 0, 0);
    }
  }
#pragma unroll
  for (int i = 0; i < 2; ++i) {
    int row4 = m0 + i * 16 + quad * 4;
    float4 nc = *(const float4*)(node_card + row4);
#pragma unroll
    for (int j = 0; j < 4; ++j) {
      int col = wave * 64 + j * 16 + l15;
      f32x4 v = acc[i][j];
      ushort4 o;
      o.x = f2bf(v[0] * nc.x);
      o.y = f2bf(v[1] * nc.y);
      o.z = f2bf(v[2] * nc.z);
      o.w = f2bf(v[3] * nc.w);
      *(ushort4*)&y0sT[(size_t)col * NN + row4] = o;
    }
  }
}

// ---------------- MM1: B1^T @ y0s (BM=128, split=8, XCD-pinned, dbuf, swz-B)
__global__ __launch_bounds__(512, 4) void mm1_kernel(const unsigned char* __restrict__ pk1T,
                                                     const unsigned short* __restrict__ y0sT,
                                                     float* __restrict__ mm1p) {
  __shared__ __align__(16) unsigned short a_lds[2][128 * 40];
  __shared__ __align__(16) unsigned short b_lds[2][256 * 32];
  const int tid = threadIdx.x;
  const int wave = tid >> 6, lane = tid & 63;
  const int quad = lane >> 4, l15 = lane & 15;
  const int wm = wave >> 2, wn = wave & 3;
  const int bid = blockIdx.x;
  const int sp = bid & 7;            // XCD-pinned K-split
  const int m0 = (bid >> 3) * 128;   // e-range
  const int KS = NN / MM1_SPLIT;     // 2048
  const int NT = KS / 32;            // 64
  const int kbase = sp * KS;

  const int am = tid >> 2;                 // e-row within tile (0..127)
  const int akg = tid & 3;                 // logical k-group (8 bf16 = 1 byte)
  const int ajbs = akg ^ ((am >> 4) & 3);  // swizzled physical group
  const int aoff = am * 40 + ajbs * 8;
  const int brow = lane >> 2;
  const int bswz = ((lane & 3) ^ ((lane >> 3) & 3)) * 8;  // staging source col swizzle
  const int rg = (l15 >> 1) & 3;                          // B read group swizzle

  f32x4 acc[4][4];
  const f32x4 fz = {0.f, 0.f, 0.f, 0.f};
#pragma unroll
  for (int i = 0; i < 4; ++i)
#pragma unroll
    for (int j = 0; j < 4; ++j) acc[i][j] = fz;

  const unsigned char* agp = pk1T + (size_t)(m0 + am) * (NN / 8) + (kbase >> 3) + akg;
  unsigned ab_cur = agp[0];  // byte for tile 0
  unsigned ab_nxt = agp[4];  // byte for tile 1
  const unsigned char* agq = agp + 8;

  // prologue: stage tile 0 into buffer 0
#pragma unroll
  for (int i = 0; i < 2; ++i) {
    int rowbase = wave * 32 + i * 16;
    const unsigned short* g = y0sT + (size_t)(rowbase + brow) * NN + kbase + bswz;
    async_copy16(g, &b_lds[0][rowbase * 32]);
  }
  *(uint4*)&a_lds[0][aoff] = expand8(ab_cur);
  __syncthreads();

  for (int t = 0; t < NT; ++t) {
    const int cur = t & 1;
    unsigned ab_new = 0;
    if (t + 1 < NT) {  // stage tile t+1 into buffer cur^1 (uniform branch)
      const int k0n = kbase + (t + 1) * 32;
#pragma unroll
      for (int i = 0; i < 2; ++i) {
        int rowbase = wave * 32 + i * 16;
        const unsigned short* g = y0sT + (size_t)(rowbase + brow) * NN + k0n + bswz;
        async_copy16(g, &b_lds[cur ^ 1][rowbase * 32]);
      }
      *(uint4*)&a_lds[cur ^ 1][aoff] = expand8(ab_nxt);
      if (t + 2 < NT) {
        ab_new = *agq;
        agq += 4;
      }
    }
    bf16x8 af[4];
#pragma unroll
    for (int i = 0; i < 4; ++i) {
      int m = wm * 64 + i * 16 + l15;
      int jbs = quad ^ ((m >> 4) & 3);
      af[i] = *(const bf16x8*)&a_lds[cur][m * 40 + jbs * 8];
    }
#pragma unroll
    for (int j = 0; j < 4; ++j) {
      bf16x8 bfr = *(const bf16x8*)&b_lds[cur][(wn * 64 + j * 16 + l15) * 32 + (quad ^ rg) * 8];
#pragma unroll
      for (int i = 0; i < 4; ++i)
        acc[i][j] = __builtin_amdgcn_mfma_f32_16x16x32_bf16(af[i], bfr, acc[i][j], 0, 0, 0);
    }
    __syncthreads();  // drains vmcnt (tile t+1 B copies) + lgkm; buffers swap
    ab_cur = ab_nxt;
    ab_nxt = ab_new;
  }
  float* outp = mm1p + (size_t)sp * NE * CH;
#pragma unroll
  for (int i = 0; i < 4; ++i) {
    int row4 = m0 + wm * 64 + i * 16 + quad * 4;
#pragma unroll
    for (int j = 0; j < 4; ++j) {
      int col = wn * 64 + j * 16 + l15;
#pragma unroll
      for (int r = 0; r < 4; ++r) outp[(size_t)(row4 + r) * CH + col] = acc[i][j][r];
    }
  }
}

// ---------------- K3: edge finalize (float4, reduce 8 partials, /d1) -------
__global__ __launch_bounds__(256) void k3_edge_final(const float* __restrict__ mm1p,
                                                     const float* __restrict__ d1,
                                                     const float* __restrict__ b01,
                                                     float* __restrict__ out1,
                                                     unsigned short* __restrict__ x1bf) {
  const int t = threadIdx.x;
  const int e = blockIdx.x * 4 + (t >> 6);
  const int c4 = (t & 63) * 4;
  float px = 0.f, py = 0.f, pz = 0.f, pw = 0.f;
#pragma unroll
  for (int sp = 0; sp < MM1_SPLIT; ++sp) {
    float4 v = *(const float4*)&mm1p[(size_t)sp * NE * CH + (size_t)e * CH + c4];
    px += v.x; py += v.y; pz += v.z; pw += v.w;
  }
  const float rd = 1.0f / d1[e];
  const float4 b = *(const float4*)&b01[c4];
  float4 x1;
  x1.x = px * rd + b.x;
  x1.y = py * rd + b.y;
  x1.z = pz * rd + b.z;
  x1.w = pw * rd + b.w;
  float4 o;
  o.x = fmaxf(x1.x, 0.f); o.y = fmaxf(x1.y, 0.f);
  o.z = fmaxf(x1.z, 0.f); o.w = fmaxf(x1.w, 0.f);
  *(float4*)&out1[(size_t)e * CH + c4] = o;
  ushort4 xb;
  xb.x = f2bf(x1.x); xb.y = f2bf(x1.y); xb.z = f2bf(x1.z); xb.w = f2bf(x1.w);
  *(ushort4*)&x1bf[(size_t)e * CH + c4] = xb;
}

// ---------------- K5: y1 GEMM (BM=32, swizzled LDS) ----------
__global__ __launch_bounds__(256) void k5_y1(const unsigned short* __restrict__ x1bf,
                                             const unsigned short* __restrict__ W1T,
                                             const float* __restrict__ edge_card,
                                             unsigned short* __restrict__ y1sT) {
  __shared__ __align__(16) unsigned short a_lds[32 * 32];
  __shared__ __align__(16) unsigned short b_lds[256 * 32];
  const int tid = threadIdx.x;
  const int wave = tid >> 6, lane = tid & 63;
  const int quad = lane >> 4, l15 = lane & 15;
  const int m0 = blockIdx.x * 32;  // e-range
  const int bswz = ((lane & 3) ^ ((lane >> 3) & 3)) * 8;
  const int rg = (l15 >> 1) & 3;

  f32x4 acc[2][4];
  const f32x4 fz = {0.f, 0.f, 0.f, 0.f};
#pragma unroll
  for (int i = 0; i < 2; ++i)
#pragma unroll
    for (int j = 0; j < 4; ++j) acc[i][j] = fz;

  for (int k0 = 0; k0 < CH; k0 += 32) {
    __syncthreads();
    if (wave < 2) {  // A: 16 rows per wave, async copy (guard: a_lds has 32 rows)
      const unsigned short* g = x1bf + (size_t)(m0 + wave * 16 + (lane >> 2)) * CH + k0 + bswz;
      async_copy16(g, &a_lds[(wave * 16) * 32]);
    }
#pragma unroll
    for (int i = 0; i < 4; ++i) {
      int rowbase = wave * 64 + i * 16;
      const unsigned short* g = W1T + (size_t)(rowbase + (lane >> 2)) * CH + k0 + bswz;
      async_copy16(g, &b_lds[rowbase * 32]);
    }
    __syncthreads();
    bf16x8 af[2];
#pragma unroll
    for (int i = 0; i < 2; ++i)
      af[i] = *(const bf16x8*)&a_lds[(i * 16 + l15) * 32 + (quad ^ rg) * 8];
#pragma unroll
    for (int j = 0; j < 4; ++j) {
      bf16x8 bfr = *(const bf16x8*)&b_lds[(wave * 64 + j * 16 + l15) * 32 + (quad ^ rg) * 8];
#pragma unroll
      for (int i = 0; i < 2; ++i)
        acc[i][j] = __builtin_amdgcn_mfma_f32_16x16x32_bf16(af[i], bfr, acc[i][j], 0, 0, 0);
    }
  }
#pragma unroll
  for (int i = 0; i < 2; ++i) {
    int row4 = m0 + i * 16 + quad * 4;
    float4 ec = *(const float4*)(edge_card + row4);
#pragma unroll
    for (int j = 0; j < 4; ++j) {
      int col = wave * 64 + j * 16 + l15;
      f32x4 v = acc[i][j];
      ushort4 o;
      o.x = f2bf(v[0] * ec.x);
      o.y = f2bf(v[1] * ec.y);
      o.z = f2bf(v[2] * ec.z);
      o.w = f2bf(v[3] * ec.w);
      *(ushort4*)&y1sT[(size_t)col * NE + row4] = o;
    }
  }
}

// ---------------- MM2: B1 @ y1s (BM=128, split=4, XCD pair, dbuf, swz-B) ----
__global__ __launch_bounds__(512, 4) void mm2_kernel(const unsigned char* __restrict__ pk1,
                                                     const unsigned short* __restrict__ y1sT,
                                                     float* __restrict__ mm2p) {
  __shared__ __align__(16) unsigned short a_lds[2][128 * 40];
  __shared__ __align__(16) unsigned short b_lds[2][256 * 32];
  const int tid = threadIdx.x;
  const int wave = tid >> 6, lane = tid & 63;
  const int quad = lane >> 4, l15 = lane & 15;
  const int wm = wave >> 2, wn = wave & 3;
  const int bid = blockIdx.x;
  const int sp = (bid >> 1) & 3;                         // XCD pair {2sp,2sp+1}
  const int m0 = (((bid >> 3) << 1) | (bid & 1)) * 128;  // node-range
  const int KS = NE / MM2_SPLIT;                         // 2048
  const int NT = KS / 32;                                // 64
  const int kbase = sp * KS;

  const int am = tid >> 2;
  const int akg = tid & 3;
  const int ajbs = akg ^ ((am >> 4) & 3);
  const int aoff = am * 40 + ajbs * 8;
  const int brow = lane >> 2;
  const int bswz = ((lane & 3) ^ ((lane >> 3) & 3)) * 8;
  const int rg = (l15 >> 1) & 3;

  f32x4 acc[4][4];
  const f32x4 fz = {0.f, 0.f, 0.f, 0.f};
#pragma unroll
  for (int i = 0; i < 4; ++i)
#pragma unroll
    for (int j = 0; j < 4; ++j) acc[i][j] = fz;

  const unsigned char* agp = pk1 + (size_t)(m0 + am) * (NE / 8) + (kbase >> 3) + akg;
  unsigned ab_cur = agp[0];
  unsigned ab_nxt = agp[4];
  const unsigned char* agq = agp + 8;

  // prologue: stage tile 0 into buffer 0
#pragma unroll
  for (int i = 0; i < 2; ++i) {
    int rowbase = wave * 32 + i * 16;
    const unsigned short* g = y1sT + (size_t)(rowbase + brow) * NE + kbase + bswz;
    async_copy16(g, &b_lds[0][rowbase * 32]);
  }
  *(uint4*)&a_lds[0][aoff] = expand8(ab_cur);
  __syncthreads();

  for (int t = 0; t < NT; ++t) {
    const int cur = t & 1;
    unsigned ab_new = 0;
    if (t + 1 < NT) {
      const int k0n = kbase + (t + 1) * 32;
#pragma unroll
      for (int i = 0; i < 2; ++i) {
        int rowbase = wave * 32 + i * 16;
        const unsigned short* g = y1sT + (size_t)(rowbase + brow) * NE + k0n + bswz;
        async_copy16(g, &b_lds[cur ^ 1][rowbase * 32]);
      }
      *(uint4*)&a_lds[cur ^ 1][aoff] = expand8(ab_nxt);
      if (t + 2 < NT) {
        ab_new = *agq;
        agq += 4;
      }
    }
    bf16x8 af[4];
#pragma unroll
    for (int i = 0; i < 4; ++i) {
      int m = wm * 64 + i * 16 + l15;
      int jbs = quad ^ ((m >> 4) & 3);
      af[i] = *(const bf16x8*)&a_lds[cur][m * 40 + jbs * 8];
    }
#pragma unroll
    for (int j = 0; j < 4; ++j) {
      bf16x8 bfr = *(const bf16x8*)&b_lds[cur][(wn * 64 + j * 16 + l15) * 32 + (quad ^ rg) * 8];
#pragma unroll
      for (int i = 0; i < 4; ++i)
        acc[i][j] = __builtin_amdgcn_mfma_f32_16x16x32_bf16(af[i], bfr, acc[i][j], 0, 0, 0);
    }
    __syncthreads();
    ab_cur = ab_nxt;
    ab_nxt = ab_new;
  }
  float* outp = mm2p + (size_t)sp * NN * CH;
#pragma unroll
  for (int i = 0; i < 4; ++i) {
    int row4 = m0 + wm * 64 + i * 16 + quad * 4;
#pragma unroll
    for (int j = 0; j < 4; ++j) {
      int col = wn * 64 + j * 16 + l15;
#pragma unroll
      for (int r = 0; r < 4; ++r) outp[(size_t)(row4 + r) * CH + col] = acc[i][j][r];
    }
  }
}

// ---------------- K6: node finalize (float4, reduce 4 partials, /d0) -------
__global__ __launch_bounds__(256) void k6_node_final(const float* __restrict__ mm2p,
                                                     const float* __restrict__ d0,
                                                     const float* __restrict__ b10,
                                                     float* __restrict__ out0) {
  const int t = threadIdx.x;
  const int n = blockIdx.x * 4 + (t >> 6);
  const int c4 = (t & 63) * 4;
  float sx = 0.f, sy = 0.f, sz = 0.f, sw = 0.f;
#pragma unroll
  for (int sp = 0; sp < MM2_SPLIT; ++sp) {
    float4 v = *(const float4*)&mm2p[(size_t)sp * NN * CH + (size_t)n * CH + c4];
    sx += v.x; sy += v.y; sz += v.z; sw += v.w;
  }
  const float rd = 1.0f / d0[n];
  const float4 b = *(const float4*)&b10[c4];
  float4 o;
  o.x = fmaxf(sx * rd + b.x, 0.f);
  o.y = fmaxf(sy * rd + b.y, 0.f);
  o.z = fmaxf(sz * rd + b.z, 0.f);
  o.w = fmaxf(sw * rd + b.w, 0.f);
  *(float4*)&out0[(size_t)n * CH + c4] = o;
}

extern "C" void kernel_launch(void* const* d_in, const int* in_sizes, int n_in,
                              void* d_out, int out_size, void* d_ws, size_t ws_size,
                              hipStream_t stream) {
  const float* x0 = (const float*)d_in[0];
  const float* B1 = (const float*)d_in[1];
  const float* W0 = (const float*)d_in[2];
  const float* W1 = (const float*)d_in[3];
  const float* b01 = (const float*)d_in[4];
  const float* b10 = (const float*)d_in[5];
  float* out0 = (float*)d_out;
  float* out1 = out0 + (size_t)NN * CH;

  char* ws = (char*)d_ws;
  size_t off = 0;
  auto take = [&](size_t bytes) {
    void* p = ws + off;
    off += (bytes + 255) & ~(size_t)255;
    return p;
  };
  unsigned short* y0sT = (unsigned short*)take((size_t)256 * NN * 2);          // 8.4 MB
  unsigned short* y1sT = (unsigned short*)take((size_t)256 * NE * 2);          // 4.2 MB
  unsigned short* x1bf = (unsigned short*)take((size_t)NE * CH * 2);           // 4.2 MB
  float* mm1p = (float*)take((size_t)MM1_SPLIT * NE * CH * 4);                 // 67.1 MB
  float* mm2p = mm1p;  // alias: mm1p dead after K3; MM2_SPLIT*NN*CH*4 == same size
  float* node_card = (float*)take((size_t)NN * 4);
  float* edge_card = (float*)take((size_t)NE * 4);
  float* d1 = (float*)take((size_t)NE * 4);
  float* d0 = (float*)take((size_t)NN * 4);
  unsigned short* W0T = (unsigned short*)take((size_t)CH * CH * 2);
  unsigned short* W1T = (unsigned short*)take((size_t)CH * CH * 2);
  unsigned* pk1 = (unsigned*)take((size_t)NN * 256 * 4);                       // 16.8 MB packed B1
  unsigned* pk1T = (unsigned*)take((size_t)NE * 512 * 4);                      // 16.8 MB packed B1^T
  (void)ws_size; (void)in_sizes; (void)n_in; (void)out_size;

  k0_transpose_w<<<dim3(256, 2), 256, 0, stream>>>(W0, W1, W0T, W1T);
  k1_pack_card<<<NN, 256, 0, stream>>>(B1, pk1, node_card);
  k1b_bitT<<<256, 256, 0, stream>>>(pk1, pk1T);
  ke_edge<<<NE / 4, 256, 0, stream>>>(pk1T, node_card, edge_card, d1);
  kd0_node<<<NN / 4, 256, 0, stream>>>(pk1, edge_card, d0);
  k2_y0<<<NN / 32, 256, 0, stream>>>(x0, W0T, node_card, y0sT);
  mm1_kernel<<<512, 512, 0, stream>>>((const unsigned char*)pk1T, y0sT, mm1p);
  k3_edge_final<<<NE / 4, 256, 0, stream>>>(mm1p, d1, b01, out1, x1bf);
  k5_y1<<<NE / 32, 256, 0, stream>>>(x1bf, W1T, edge_card, y1sT);
  mm2_kernel<<<512, 512, 0, stream>>>((const unsigned char*)pk1, y1sT, mm2p);
  k6_node_final<<<NN / 4, 256, 0, stream>>>(mm2p, d0, b10, out0);
}